// Round 8
// baseline (553.251 us; speedup 1.0000x reference)
//
#include <hip/hip_runtime.h>
#include <stdint.h>

#define BATCH   65536

typedef __bf16 bf16x8 __attribute__((ext_vector_type(8)));
typedef float  f32x16 __attribute__((ext_vector_type(16)));

__device__ __forceinline__ uint32_t f2bf1(float v) {
  uint32_t u = __float_as_uint(v);
  return (u + 0x7FFFu + ((u >> 16) & 1u)) >> 16;   // RNE bf16
}

__device__ __forceinline__ float fast_sigmoid(float x) {
  return __builtin_amdgcn_rcpf(1.0f + __expf(-x));
}
__device__ __forceinline__ float fast_tanh(float x) {
  return 1.0f - 2.0f * __builtin_amdgcn_rcpf(1.0f + __expf(2.0f * x));
}

// ---------------- prep: weights -> bf16 fragment image (r4 layout, conflicts=0 proven) ----------------
// 16B chunk t = nb*8192 + ks*512 + kc*128 + g*32 + u5
// holds Wcat[k = ks*32 + kc*8 + i][col = g*256 + nb*32 + u5], i = 0..7
// Wcat rows 0..255 = kernel (x), 256..511 = recurrent_kernel (h).
__global__ __launch_bounds__(256) void prep_weights(
    const float* __restrict__ wk, const float* __restrict__ wr,
    uint4* __restrict__ img) {
  int t  = blockIdx.x * 256 + threadIdx.x;   // 0..65535
  int u5 = t & 31;
  int g  = (t >> 5) & 3;
  int kc = (t >> 7) & 3;
  int ks = (t >> 9) & 15;
  int nb = t >> 13;
  int k0  = ks * 32 + kc * 8;
  int col = g * 256 + nb * 32 + u5;
  uint32_t o[4];
#pragma unroll
  for (int p = 0; p < 4; ++p) {
    int k = k0 + p * 2;
    float s0 = (k     < 256) ? wk[(size_t)k * 1024 + col]       : wr[(size_t)(k - 256) * 1024 + col];
    float s1 = (k + 1 < 256) ? wk[(size_t)(k + 1) * 1024 + col] : wr[(size_t)(k - 255) * 1024 + col];
    o[p] = f2bf1(s0) | (f2bf1(s1) << 16);
  }
  img[t] = make_uint4(o[0], o[1], o[2], o[3]);
}

// ---------------- persistent fused LSTM: whole B panel in LDS, zero main-loop barriers ----------------
// 256 blocks (1/CU via 128KB LDS) x 512 thr (8 waves, 2/SIMD).
// Block owns nb (32 units): stages its 128KB B panel ONCE, then 8 iterations of
// 256 rows: per wave 32 rows x 128 cols, 16 K-steps of {8 ds_read_b128 + 8 MFMA}.
// A loads are per-wave-private fragment-layout globals with 1-step prefetch; no barriers.
// blockIdx%8 -> XCD (round-robin): blocks on one XCD = 4 row-streams x 8 nb -> A rows L2-shared.
__global__ __launch_bounds__(512, 2) void lstm_fused(
    const float* __restrict__ xp, const float* __restrict__ hp,
    const float* __restrict__ cp, const float* __restrict__ bp,
    const uint4* __restrict__ img, float* __restrict__ outp) {

  __shared__ __align__(16) char smem[131072];   // full B panel: K=512 x 128 cols bf16

  const int tid  = threadIdx.x;
  const int lane = tid & 63;
  const int wv   = tid >> 6;          // 0..7
  const int ln31 = lane & 31;
  const int hi32 = lane >> 5;

  const int b    = blockIdx.x;        // 0..255
  const int q    = b >> 3;
  const int nb   = q & 7;                         // unit block (32 units)
  const int strm = (b & 7) * 4 + (q >> 3);        // row stream 0..31

  // ---- stage whole B panel (8192 chunks of 16B) once; each wave copies 16KB ----
  const uint4* bpan = img + (size_t)nb * 8192;
#pragma unroll
  for (int j = 0; j < 16; ++j) {
    const uint4* src = bpan + wv * 1024 + j * 64 + lane;       // per-lane global src
    char* dst = smem + (wv * 1024 + j * 64) * 16;              // uniform; HW adds lane*16
    __builtin_amdgcn_global_load_lds(
        (const __attribute__((address_space(1))) uint32_t*)src,
        (__attribute__((address_space(3))) uint32_t*)dst, 16, 0, 0);
  }

  const int u = nb * 32 + ln31;
  const float bi  = bp[u];
  const float bf_ = bp[256 + u];
  const float bg  = bp[512 + u];
  const float bo  = bp[768 + u];

  asm volatile("s_waitcnt vmcnt(0)" ::: "memory");
  __syncthreads();                     // the ONLY barrier

  // loop-invariant B read offsets (linear stride-16 within 512B -> conflict-free, r4-proven)
  int bro[8];
#pragma unroll
  for (int hh = 0; hh < 2; ++hh)
#pragma unroll
    for (int g = 0; g < 4; ++g)
      bro[hh * 4 + g] = (hh * 2 + hi32) * 2048 + g * 512 + ln31 * 16;

  float* outh = outp;
  float* outc = outp + (size_t)BATCH * 256;

  // A pointers for iteration t=0 (row = group*256 + wv*32 + ln31; +65536 floats per iter)
  const int grow0 = (strm * 8) * 256 + wv * 32;
  const float* xb = xp + (size_t)(grow0 + ln31) * 256 + hi32 * 8;
  const float* hb = hp + (size_t)(grow0 + ln31) * 256 + hi32 * 8;

  float4 areg[2][4];
  auto loadA = [&](const float* xbase, const float* hbase, int ks, float4* A) {
    const float* s = ((ks < 8) ? xbase : hbase) + (ks & 7) * 32;
    A[0] = *(const float4*)(s);
    A[1] = *(const float4*)(s + 4);
    A[2] = *(const float4*)(s + 16);
    A[3] = *(const float4*)(s + 20);
  };

  f32x16 acc[4];
#pragma unroll
  for (int g = 0; g < 4; ++g)
#pragma unroll
    for (int i = 0; i < 16; ++i) acc[g][i] = 0.0f;

  loadA(xb, hb, 0, areg[0]);           // prologue: A(t=0, ks=0)

  for (int t = 0; t < 8; ++t) {        // rolled: 8 row-group iterations
    const int grow = grow0 + t * 256;  // group*256 + wv*32

    // prefetch c for this iteration (NT: read-once, don't pollute L2)
    float cr[16];
#pragma unroll
    for (int r = 0; r < 16; ++r) {
      int orow = grow + 4 * hi32 + (r & 3) + 8 * (r >> 2);
      cr[r] = __builtin_nontemporal_load(cp + (size_t)orow * 256 + u);
    }

#pragma unroll
    for (int ks = 0; ks < 16; ++ks) {
      // 1-step A prefetch (16 regs — the size the compiler provably keeps live, r3)
      if (ks < 15)      loadA(xb, hb, ks + 1, areg[(ks + 1) & 1]);
      else if (t < 7)   loadA(xb + 65536, hb + 65536, 0, areg[0]);

      bf16x8 F[2];
#pragma unroll
      for (int h = 0; h < 2; ++h) {
        float4 lo = areg[ks & 1][h * 2], hi = areg[ks & 1][h * 2 + 1];
        bf16x8 f;
        f[0] = (__bf16)lo.x; f[1] = (__bf16)lo.y; f[2] = (__bf16)lo.z; f[3] = (__bf16)lo.w;
        f[4] = (__bf16)hi.x; f[5] = (__bf16)hi.y; f[6] = (__bf16)hi.z; f[7] = (__bf16)hi.w;
        F[h] = f;
      }

      const char* bbase = smem + ks * 8192;
      bf16x8 B[8];
#pragma unroll
      for (int r8 = 0; r8 < 8; ++r8)
        B[r8] = *(const bf16x8*)(bbase + bro[r8]);

      __builtin_amdgcn_s_setprio(1);
#pragma unroll
      for (int h = 0; h < 2; ++h)
#pragma unroll
        for (int g = 0; g < 4; ++g)
          acc[g] = __builtin_amdgcn_mfma_f32_32x32x16_bf16(F[h], B[h * 4 + g], acc[g], 0, 0, 0);
      __builtin_amdgcn_s_setprio(0);
    }

    // ---- per-iteration epilogue: gates + cell update, NT streaming ----
#pragma unroll
    for (int r = 0; r < 16; ++r) {
      int orow = grow + 4 * hi32 + (r & 3) + 8 * (r >> 2);
      size_t idx = (size_t)orow * 256 + u;
      float zi = acc[0][r] + bi;
      float zf = acc[1][r] + bf_;
      float zg = acc[2][r] + bg;
      float zo = acc[3][r] + bo;
      float iv = fast_sigmoid(zi);
      float fv = fast_sigmoid(zf);
      float gv = fast_tanh(zg);
      float ov = fast_sigmoid(zo);
      float cn = fv * cr[r] + iv * gv;
      float hn = ov * fast_tanh(cn);
      __builtin_nontemporal_store(hn, outh + idx);
      __builtin_nontemporal_store(cn, outc + idx);
    }

#pragma unroll
    for (int g = 0; g < 4; ++g)
#pragma unroll
      for (int i = 0; i < 16; ++i) acc[g][i] = 0.0f;

    xb += 65536;                       // next 256 rows
    hb += 65536;
  }
}

extern "C" void kernel_launch(void* const* d_in, const int* in_sizes, int n_in,
                              void* d_out, int out_size, void* d_ws, size_t ws_size,
                              hipStream_t stream) {
  const float* x  = (const float*)d_in[0];
  const float* h  = (const float*)d_in[1];
  const float* c  = (const float*)d_in[2];
  const float* wk = (const float*)d_in[3];
  const float* wr = (const float*)d_in[4];
  const float* b  = (const float*)d_in[5];
  prep_weights<<<256, 256, 0, stream>>>(wk, wr, (uint4*)d_ws);   // 1 MB bf16 image
  lstm_fused<<<256, 512, 0, stream>>>(x, h, c, b,
                                      (const uint4*)d_ws, (float*)d_out);
}

// Round 9
// 149.174 us; speedup vs baseline: 3.7088x; 3.7088x over previous
//
#include <hip/hip_runtime.h>
#include <stdint.h>

#define BATCH 65536

typedef __bf16 bf16x8 __attribute__((ext_vector_type(8)));
typedef float  f32x16 __attribute__((ext_vector_type(16)));

__device__ __forceinline__ uint32_t f2bf1(float v) {
  uint32_t u = __float_as_uint(v);
  return (u + 0x7FFFu + ((u >> 16) & 1u)) >> 16;   // RNE bf16
}

__device__ __forceinline__ float fast_sigmoid(float x) {
  return __builtin_amdgcn_rcpf(1.0f + __expf(-x));
}
__device__ __forceinline__ float fast_tanh(float x) {
  return 1.0f - 2.0f * __builtin_amdgcn_rcpf(1.0f + __expf(2.0f * x));
}

// ---------------- prep: weights -> bf16 fragment image (r4 layout, conflicts=0 proven) ----------------
// 16B chunk t = nb*8192 + ks*512 + kc*128 + g*32 + u5
// holds Wcat[k = ks*32 + kc*8 + i][col = g*256 + nb*32 + u5], i = 0..7
// Wcat rows 0..255 = kernel (x), 256..511 = recurrent_kernel (h).
__global__ __launch_bounds__(256) void prep_weights(
    const float* __restrict__ wk, const float* __restrict__ wr,
    uint4* __restrict__ img) {
  int t  = blockIdx.x * 256 + threadIdx.x;   // 0..65535
  int u5 = t & 31;
  int g  = (t >> 5) & 3;
  int kc = (t >> 7) & 3;
  int ks = (t >> 9) & 15;
  int nb = t >> 13;
  int k0  = ks * 32 + kc * 8;
  int col = g * 256 + nb * 32 + u5;
  uint32_t o[4];
#pragma unroll
  for (int p = 0; p < 4; ++p) {
    int k = k0 + p * 2;
    float s0 = (k     < 256) ? wk[(size_t)k * 1024 + col]       : wr[(size_t)(k - 256) * 1024 + col];
    float s1 = (k + 1 < 256) ? wk[(size_t)(k + 1) * 1024 + col] : wr[(size_t)(k - 255) * 1024 + col];
    o[p] = f2bf1(s0) | (f2bf1(s1) << 16);
  }
  img[t] = make_uint4(o[0], o[1], o[2], o[3]);
}

// ---------------- persistent fused LSTM: whole B panel in LDS once, minimal live set ----------------
// 256 blocks (1/CU, 128KB LDS) x 512 thr (8 waves, 2/SIMD). Block owns nb (32 units).
// After the single staging barrier: 8 groups x 16 K-steps, zero barriers, zero B global traffic.
// Per wave-step: 8 ds_read_b128 (conflict-free) + 8 MFMA + 4 global A loads (depth-1 prefetch).
// blockIdx%8 -> XCD: the 8 nb-sharers of each A row-stream are co-resident on one XCD (L2 dedup).
__global__ __launch_bounds__(512, 2) void lstm_fused(
    const float* __restrict__ xp, const float* __restrict__ hp,
    const float* __restrict__ cp, const float* __restrict__ bp,
    const uint4* __restrict__ img, float* __restrict__ outp) {

  __shared__ __align__(16) char smem[131072];   // full B panel: K=512 x 128 cols bf16

  const int tid  = threadIdx.x;
  const int lane = tid & 63;
  const int wv   = tid >> 6;          // 0..7
  const int ln31 = lane & 31;
  const int hi32 = lane >> 5;

  const int b    = blockIdx.x;        // 0..255
  const int q    = b >> 3;
  const int nb   = q & 7;                         // unit block (32 units)
  const int strm = (b & 7) * 4 + (q >> 3);        // row stream 0..31 (2048 rows each)

  // ---- stage whole B panel once (each wave 16 KB via 16 x 1KB DMA) ----
  const uint4* bpan = img + (size_t)nb * 8192;
#pragma unroll
  for (int j = 0; j < 16; ++j) {
    const uint4* src = bpan + wv * 1024 + j * 64 + lane;
    char* dst = smem + (wv * 1024 + j * 64) * 16;          // uniform base; HW adds lane*16
    __builtin_amdgcn_global_load_lds(
        (const __attribute__((address_space(1))) uint32_t*)src,
        (__attribute__((address_space(3))) uint32_t*)dst, 16, 0, 0);
  }

  const int u = nb * 32 + ln31;
  const float bi  = bp[u];
  const float bf_ = bp[256 + u];
  const float bg  = bp[512 + u];
  const float bo  = bp[768 + u];

  asm volatile("s_waitcnt vmcnt(0)" ::: "memory");
  __syncthreads();                     // the ONLY barrier

  // lane-dependent B base; all further B addressing is compile-time immediates:
  // byte = lb + ks*8192 + h*4096 + g*512   (chunk = ks*512 + (h*2+hi32)*128 + g*32 + ln31)
  const char* lb = smem + hi32 * 2048 + ln31 * 16;

  const int grow0 = strm * 2048 + wv * 32;       // first row of this wave's group-0 tile
  const float* xb = xp + (size_t)(grow0 + ln31) * 256 + hi32 * 8;
  const float* hb = hp + (size_t)(grow0 + ln31) * 256 + hi32 * 8;

  float4 areg[2][4];
  auto loadA = [&](const float* base, int k7, float4* A) {
    const float* s = base + k7 * 32;
    A[0] = *(const float4*)(s);
    A[1] = *(const float4*)(s + 4);
    A[2] = *(const float4*)(s + 16);
    A[3] = *(const float4*)(s + 20);
  };

  f32x16 acc[4];
#pragma unroll
  for (int g = 0; g < 4; ++g)
#pragma unroll
    for (int i = 0; i < 16; ++i) acc[g][i] = 0.0f;

  loadA(xb, 0, areg[0]);               // prologue: A(group 0, ks 0)

  for (int t = 0; t < 8; ++t) {        // 8 row-group iterations (rolled)
    const float* nxb = xb + ((t < 7) ? 65536 : 0);   // next-group x base (clamped: harmless re-read)

#pragma unroll
    for (int ks = 0; ks < 16; ++ks) {
      // depth-1 A prefetch into the other buffer (parity: consume ks&1, fill (ks+1)&1; 16 even
      // so group boundary keeps parity: A(next,0) lands in buf 0, consumed at next ks=0)
      if (ks < 7)        loadA(xb, ks + 1, areg[(ks + 1) & 1]);
      else if (ks == 7)  loadA(hb, 0, areg[0]);
      else if (ks < 15)  loadA(hb, ks - 7, areg[(ks + 1) & 1]);
      else               loadA(nxb, 0, areg[0]);

      const char* bstep = lb + ks * 8192;
#pragma unroll
      for (int h = 0; h < 2; ++h) {
        // fp32 -> bf16 A fragment for this 16-k half
        float4 lo = areg[ks & 1][h * 2], hi = areg[ks & 1][h * 2 + 1];
        bf16x8 F;
        F[0] = (__bf16)lo.x; F[1] = (__bf16)lo.y; F[2] = (__bf16)lo.z; F[3] = (__bf16)lo.w;
        F[4] = (__bf16)hi.x; F[5] = (__bf16)hi.y; F[6] = (__bf16)hi.z; F[7] = (__bf16)hi.w;
        // 4 B fragments (16 VGPR transient), then 4 MFMA
        bf16x8 B0 = *(const bf16x8*)(bstep + h * 4096);
        bf16x8 B1 = *(const bf16x8*)(bstep + h * 4096 + 512);
        bf16x8 B2 = *(const bf16x8*)(bstep + h * 4096 + 1024);
        bf16x8 B3 = *(const bf16x8*)(bstep + h * 4096 + 1536);
        __builtin_amdgcn_s_setprio(1);
        acc[0] = __builtin_amdgcn_mfma_f32_32x32x16_bf16(F, B0, acc[0], 0, 0, 0);
        acc[1] = __builtin_amdgcn_mfma_f32_32x32x16_bf16(F, B1, acc[1], 0, 0, 0);
        acc[2] = __builtin_amdgcn_mfma_f32_32x32x16_bf16(F, B2, acc[2], 0, 0, 0);
        acc[3] = __builtin_amdgcn_mfma_f32_32x32x16_bf16(F, B3, acc[3], 0, 0, 0);
        __builtin_amdgcn_s_setprio(0);
      }
    }

    // ---- per-group epilogue: gates + cell update; c NT-loaded here (no long-lived prefetch) ----
    {
      const size_t obase = (size_t)(grow0 + t * 256 + 4 * hi32) * 256 + u;
      const float* cb = cp + obase;
      float* oh = outp + obase;
      float* oc = outp + (size_t)BATCH * 256 + obase;
#pragma unroll
      for (int r = 0; r < 16; ++r) {
        const int off = ((r & 3) + 8 * (r >> 2)) * 256;
        float cv = __builtin_nontemporal_load(cb + off);
        float zi = acc[0][r] + bi;
        float zf = acc[1][r] + bf_;
        float zg = acc[2][r] + bg;
        float zo = acc[3][r] + bo;
        float iv = fast_sigmoid(zi);
        float fv = fast_sigmoid(zf);
        float gv = fast_tanh(zg);
        float ov = fast_sigmoid(zo);
        float cn = fv * cv + iv * gv;
        float hn = ov * fast_tanh(cn);
        __builtin_nontemporal_store(hn, oh + off);
        __builtin_nontemporal_store(cn, oc + off);
      }
    }

#pragma unroll
    for (int g = 0; g < 4; ++g)
#pragma unroll
      for (int i = 0; i < 16; ++i) acc[g][i] = 0.0f;

    xb = nxb;
    hb += (t < 7) ? 65536 : 0;
  }
}

extern "C" void kernel_launch(void* const* d_in, const int* in_sizes, int n_in,
                              void* d_out, int out_size, void* d_ws, size_t ws_size,
                              hipStream_t stream) {
  const float* x  = (const float*)d_in[0];
  const float* h  = (const float*)d_in[1];
  const float* c  = (const float*)d_in[2];
  const float* wk = (const float*)d_in[3];
  const float* wr = (const float*)d_in[4];
  const float* b  = (const float*)d_in[5];
  prep_weights<<<256, 256, 0, stream>>>(wk, wr, (uint4*)d_ws);   // 1 MB bf16 image
  lstm_fused<<<256, 512, 0, stream>>>(x, h, c, b,
                                      (const uint4*)d_ws, (float*)d_out);
}